// Round 11
// baseline (83.560 us; speedup 1.0000x reference)
//
#include <hip/hip_runtime.h>

// Mamba-2 SSD forward. B=2, L=4096, H=16, P=S=64, chunk=64, n=64 chunks.
// ssd_f (512 thr, wave-specialized): stage B,C (rm) + B^T,(dte∘X)^T (tr) once;
//        waves 0-3: M = L∘(C·B^T) -> Mws (frag-native);
//        waves 4-7: h_final -> hws (frag-native). Runs both halves CONCURRENTLY.
// ssd_scan: element-wise inter-chunk scan on frag-native hws (4-deep pipeline).
// ssd_y:  LDS-free, barrier-free backend: Y^T = X^T·M^T + E∘(h^T·C^T),
//         C read direct, decay-from-start exact in fp32 epilogue.

#define BSZ 2
#define LSEQ 4096
#define NH 16
#define NC 64
#define NCH (BSZ * NH * NC)      // 2048 chunk tasks
#define SCAN_G 8
#define CHW 4096                 // ushort elems per chunk ws tile
#define TILE_USHORTS ((size_t)NCH * CHW)

typedef float f32x4 __attribute__((ext_vector_type(4)));
typedef __bf16 bf16x8 __attribute__((ext_vector_type(8)));

union FragU { uint4 u; bf16x8 b; unsigned short s[8]; };

__device__ __forceinline__ unsigned short f2b(float x) {
    union { float f; unsigned u; } c; c.f = x;
    unsigned r = c.u + 0x7fffu + ((c.u >> 16) & 1u);   // RNE bf16
    return (unsigned short)(r >> 16);
}
__device__ __forceinline__ float b2f(unsigned short v) {
    union { unsigned u; float f; } c; c.u = ((unsigned)v) << 16;
    return c.f;
}

// LDS element-index swizzles, 64 ushort per row
__device__ __forceinline__ int rm_e(int row, int k) { return row * 64 + (k ^ ((row & 7) << 3)); }
__device__ __forceinline__ int tr_e(int row, int k) { return row * 64 + (k ^ (((row >> 1) & 7) << 3)); }

__device__ __forceinline__ bf16x8 frag_rm(const unsigned short* buf, int tile, int kk, int l) {
    FragU f; f.u = *(const uint4*)&buf[rm_e(tile * 16 + (l & 15), kk * 32 + ((l >> 4) << 3))];
    return f.b;
}
__device__ __forceinline__ bf16x8 frag_tr(const unsigned short* buf, int tile, int kk, int l) {
    FragU f; f.u = *(const uint4*)&buf[tr_e(tile * 16 + (l & 15), kk * 32 + ((l >> 4) << 3))];
    return f.b;
}

__device__ __forceinline__ bf16x8 pack8(const float4 a, const float4 b) {
    FragU f;
    f.s[0] = f2b(a.x); f.s[1] = f2b(a.y); f.s[2] = f2b(a.z); f.s[3] = f2b(a.w);
    f.s[4] = f2b(b.x); f.s[5] = f2b(b.y); f.s[6] = f2b(b.z); f.s[7] = f2b(b.w);
    return f.b;
}

// ---------------- ssd_f: wave-specialized frontend (512 threads) ----------------
__global__ __launch_bounds__(512) void ssd_f(
    const float* __restrict__ Xg, const float* __restrict__ Ag,
    const float* __restrict__ Bg, const float* __restrict__ Cg,
    unsigned short* __restrict__ hws, unsigned short* __restrict__ Mws,
    float* __restrict__ dws)
{
    __shared__ __align__(16) unsigned short sB[64 * 64];   // B rm [j][s]
    __shared__ __align__(16) unsigned short sC[64 * 64];   // C rm [i][s]
    __shared__ __align__(16) unsigned short sBt[64 * 64];  // B^T tr [s][c]
    __shared__ __align__(16) unsigned short sXt[64 * 64];  // (dte∘X)^T tr [p][c]
    __shared__ float sE[64], sR[64], sDte[64];

    const int tid = threadIdx.x;
    const int l = tid & 63;
    const int w = tid >> 6;                  // 8 waves
    const int n = blockIdx.x & (NC - 1);
    const int h = (blockIdx.x >> 6) & (NH - 1);
    const int b = blockIdx.x >> 10;
    const int row0 = b * LSEQ + n * 64;
    const unsigned chb = (unsigned)blockIdx.x * CHW;
    const int i15 = l & 15;

    // --- issue staging loads: each thread owns row c = tid>>3, 8 cols at e8 ---
    const int c = tid >> 3;
    const int e8 = (tid & 7) << 3;
    const unsigned g = ((unsigned)(row0 + c) * NH + h) * 64 + e8;
    const float4 b0 = *(const float4*)&Bg[g];
    const float4 b1 = *(const float4*)&Bg[g + 4];
    const float4 c0 = *(const float4*)&Cg[g];
    const float4 c1 = *(const float4*)&Cg[g + 4];
    const float4 x0 = *(const float4*)&Xg[g];
    const float4 x1 = *(const float4*)&Xg[g + 4];

    // --- wave0: cumsum of A -> decay tables ---
    if (tid < 64) {
        float a = Ag[(unsigned)(row0 + tid) * NH + h];
        #pragma unroll
        for (int off = 1; off < 64; off <<= 1) {
            float v = __shfl_up(a, off, 64);
            if (tid >= off) a += v;
        }
        const float a63 = __shfl(a, 63, 64);
        sE[tid] = __expf(a);
        sR[tid] = __expf(-a);
        sDte[tid] = __expf(a63 - a);
        if (tid == 63) dws[blockIdx.x] = __expf(a63);
    }
    __syncthreads();

    // --- stage all 4 tiles ---
    {
        const float dte = sDte[c];
        ushort4 bw0, bw1, cw0, cw1;
        bw0.x = f2b(b0.x); bw0.y = f2b(b0.y); bw0.z = f2b(b0.z); bw0.w = f2b(b0.w);
        bw1.x = f2b(b1.x); bw1.y = f2b(b1.y); bw1.z = f2b(b1.z); bw1.w = f2b(b1.w);
        cw0.x = f2b(c0.x); cw0.y = f2b(c0.y); cw0.z = f2b(c0.z); cw0.w = f2b(c0.w);
        cw1.x = f2b(c1.x); cw1.y = f2b(c1.y); cw1.z = f2b(c1.z); cw1.w = f2b(c1.w);
        *(ushort4*)&sB[rm_e(c, e8)] = bw0;
        *(ushort4*)&sB[rm_e(c, e8 + 4)] = bw1;
        *(ushort4*)&sC[rm_e(c, e8)] = cw0;
        *(ushort4*)&sC[rm_e(c, e8 + 4)] = cw1;
        sBt[tr_e(e8 + 0, c)] = bw0.x; sBt[tr_e(e8 + 1, c)] = bw0.y;
        sBt[tr_e(e8 + 2, c)] = bw0.z; sBt[tr_e(e8 + 3, c)] = bw0.w;
        sBt[tr_e(e8 + 4, c)] = bw1.x; sBt[tr_e(e8 + 5, c)] = bw1.y;
        sBt[tr_e(e8 + 6, c)] = bw1.z; sBt[tr_e(e8 + 7, c)] = bw1.w;
        sXt[tr_e(e8 + 0, c)] = f2b(x0.x * dte); sXt[tr_e(e8 + 1, c)] = f2b(x0.y * dte);
        sXt[tr_e(e8 + 2, c)] = f2b(x0.z * dte); sXt[tr_e(e8 + 3, c)] = f2b(x0.w * dte);
        sXt[tr_e(e8 + 4, c)] = f2b(x1.x * dte); sXt[tr_e(e8 + 5, c)] = f2b(x1.y * dte);
        sXt[tr_e(e8 + 6, c)] = f2b(x1.z * dte); sXt[tr_e(e8 + 7, c)] = f2b(x1.w * dte);
    }
    __syncthreads();

    const f32x4 zero = {0.f, 0.f, 0.f, 0.f};
    const int il = (l >> 4) << 2;

    if (w < 4) {
        // --- waves 0-3: mm1 CB[i][j] = sum_s C[i][s]B[j][s]; wave owns i-slab ---
        bf16x8 aC2[2];
        #pragma unroll
        for (int kk = 0; kk < 2; ++kk) aC2[kk] = frag_rm(sC, w, kk, l);
        f32x4 accT[4] = {zero, zero, zero, zero};
        #pragma unroll
        for (int kk = 0; kk < 2; ++kk) {
            #pragma unroll
            for (int tj = 0; tj < 4; ++tj)
                accT[tj] = __builtin_amdgcn_mfma_f32_16x16x32_bf16(aC2[kk], frag_rm(sB, tj, kk, l), accT[tj], 0, 0, 0);
        }
        // lane holds CB[i=w16+il+r][j=tj*16+i15] -> store M^T frag-native:
        // Mws element r of lane l, tile (tj,w): M[j][i] layout for backend B-frags.
        // Backend expects Mws[(((ti*4+wj)*64 + lane)<<2)+r] = M[i=ti*16+(lane&15)][j=wj*16+(lane>>4)*4+r]
        // Our accT has D[i-slab w][j]; rewrite per backend mapping: i fixed per (w,il,r)... so store via
        // the transposed-assignment: for tile ti=our-tj, lane' = ... simplest: swap roles -> compute
        // M with A=B,Bop=C instead. (Done below: we computed CB with A=C; emit M^T by indexing.)
        const int j0 = il;                  // within-tile j offset of reg r is tj*16 + i15? no:
        // accT[tj][r] = CB[i = w*16+il+r][j = tj*16+i15]
        // Backend needs Mws[(((TJ*4+WJ)*64 + L)<<2)+r'] = M[TI_row(L,TJ)][WJ*16 + (L>>4)*4 + r']
        //   with TI_row(L,TJ) = TJ*16 + (L&15).
        // Match: set TJ = tj? We need the j-index to be the frag's k? Use direct scatter:
        #pragma unroll
        for (int tj = 0; tj < 4; ++tj) {
            #pragma unroll
            for (int r = 0; r < 4; ++r) {
                const int i = w * 16 + il + r;
                const int j = tj * 16 + i15;
                const float v = (i >= j) ? sE[i] * sR[j] * accT[tj][r] : 0.f;
                // backend mapping: element M[i][j] lives at
                // Mws[(((ti*4+wj)*64 + lane)<<2) + rr], ti=i>>4, lane=(j&15)| (((j>>2)&3)<<4)... derive:
                // i = ti*16 + (lane&15)  -> lane&15 = i&15, ti = i>>4
                // j = wj*16 + (lane>>4)*4 + rr -> wj = j>>4, lane>>4 = (j>>2)&3, rr = j&3
                const int lane = (i & 15) | (((j >> 2) & 3) << 4);
                Mws[chb + ((((i >> 4) * 4 + (j >> 4)) * 64 + lane) << 2) + (j & 3)] = f2b(v);
            }
        }
    } else {
        // --- waves 4-7: mmH  h[s][p] = sum_c B[c][s](dte∘X)[c][p]; wave owns s-slab ---
        const int w4 = w - 4;
        f32x4 accH[4] = {zero, zero, zero, zero};
        #pragma unroll
        for (int kk = 0; kk < 2; ++kk) {
            const bf16x8 aBt = frag_tr(sBt, w4, kk, l);
            #pragma unroll
            for (int tp = 0; tp < 4; ++tp)
                accH[tp] = __builtin_amdgcn_mfma_f32_16x16x32_bf16(aBt, frag_tr(sXt, tp, kk, l), accH[tp], 0, 0, 0);
        }
        // h store, fragment-native (R6-validated): elem (p=tp*16+i15, s=w4*16+il+r)
        const int kk2 = w4 >> 1;
        const int q3 = ((w4 & 1) << 1) | (il >> 3);
        const int e0 = il & 7;
        const int lt = q3 * 16 + i15;
        #pragma unroll
        for (int tp = 0; tp < 4; ++tp) {
            ushort4 o;
            o.x = f2b(accH[tp][0]); o.y = f2b(accH[tp][1]);
            o.z = f2b(accH[tp][2]); o.w = f2b(accH[tp][3]);
            *(ushort4*)&hws[chb + (((kk2 * 4 + tp) * 64 + lt) << 3) + e0] = o;
        }
    }
}

// ---------------- scan: element-wise over chunks (in-place, 4-deep) ----------------
__global__ __launch_bounds__(256) void ssd_scan(unsigned short* __restrict__ hws,
                                                const float* __restrict__ dws)
{
    __shared__ float sD[NC];
    const int tid = threadIdx.x;
    const int bh = blockIdx.x / SCAN_G;
    const int g = blockIdx.x % SCAN_G;
    if (tid < NC) sD[tid] = dws[bh * NC + tid];
    __syncthreads();

    unsigned* hw32 = (unsigned*)hws;
    const unsigned base = (unsigned)bh * NC * 2048u + g * 256u + tid;

    unsigned buf[4];
    #pragma unroll
    for (int jj = 0; jj < 4; ++jj) buf[jj] = hw32[base + jj * 2048u];

    float cx = 0.f, cy = 0.f;
    #pragma unroll 4
    for (int c = 0; c < NC; ++c) {
        const unsigned cur = buf[c & 3];
        if (c + 4 < NC) buf[c & 3] = hw32[base + (unsigned)(c + 4) * 2048u];
        hw32[base + (unsigned)c * 2048u] = (unsigned)f2b(cx) | ((unsigned)f2b(cy) << 16);
        const float d = sD[c];
        cx = d * cx + b2f((unsigned short)(cur & 0xffffu));
        cy = d * cy + b2f((unsigned short)(cur >> 16));
    }
}

// ---------------- ssd_y: LDS-free, barrier-free backend (R7 form) ----------------
// Y[i][p] = sum_j M[i][j] X[j][p] + E_i * sum_s C[i][s] h_inter[s][p]
__global__ __launch_bounds__(256) void ssd_y(
    const float* __restrict__ Xg, const float* __restrict__ Ag,
    const float* __restrict__ Cg, const unsigned short* __restrict__ Mws,
    const unsigned short* __restrict__ hws, float* __restrict__ Yg)
{
    const int tid = threadIdx.x;
    const int l = tid & 63;
    const int w = tid >> 6;
    const int n = blockIdx.x & (NC - 1);
    const int h = (blockIdx.x >> 6) & (NH - 1);
    const int b = blockIdx.x >> 10;
    const int row0 = b * LSEQ + n * 64;
    const unsigned chb = (unsigned)blockIdx.x * CHW;
    const int i15 = l & 15;
    const int p = w * 16 + i15;
    const int s0base = (l >> 4) << 3;

    float acs = Ag[(unsigned)(row0 + l) * NH + h];
    #pragma unroll
    for (int off = 1; off < 64; off <<= 1) {
        float v = __shfl_up(acs, off, 64);
        if (l >= off) acs += v;
    }

    bf16x8 aX[2], aH[2];
    #pragma unroll
    for (int kk = 0; kk < 2; ++kk) {
        const int c0 = kk * 32 + s0base;
        bf16x8 x;
        #pragma unroll
        for (int e = 0; e < 8; ++e)
            x[e] = (__bf16)Xg[((unsigned)(row0 + c0 + e) * NH + h) * 64 + p];
        aX[kk] = x;
        FragU f; f.u = *(const uint4*)&hws[chb + (((kk * 4 + w) * 64 + l) << 3)];
        aH[kk] = f.b;
    }

    const f32x4 zero = {0.f, 0.f, 0.f, 0.f};
    f32x4 accY[4] = {zero, zero, zero, zero};
    f32x4 accI[4] = {zero, zero, zero, zero};
    #pragma unroll
    for (int kk = 0; kk < 2; ++kk) {
        const int j0 = kk * 32 + s0base;
        const int wj = j0 >> 4;
        const int q = (j0 >> 2) & 3;
        #pragma unroll
        for (int ti = 0; ti < 4; ++ti) {
            FragU mf;
            *(ushort4*)&mf.s[0] = *(const ushort4*)&Mws[chb + (((ti * 4 + wj) * 64 + q * 16 + i15) << 2)];
            *(ushort4*)&mf.s[4] = *(const ushort4*)&Mws[chb + (((ti * 4 + wj) * 64 + (q + 1) * 16 + i15) << 2)];
            const int i = ti * 16 + i15;
            const unsigned g = ((unsigned)(row0 + i) * NH + h) * 64 + kk * 32 + s0base;
            const bf16x8 cf = pack8(*(const float4*)&Cg[g], *(const float4*)&Cg[g + 4]);
            accY[ti] = __builtin_amdgcn_mfma_f32_16x16x32_bf16(aX[kk], mf.b, accY[ti], 0, 0, 0);
            accI[ti] = __builtin_amdgcn_mfma_f32_16x16x32_bf16(aH[kk], cf, accI[ti], 0, 0, 0);
        }
    }

    const int pbase = w * 16 + ((l >> 4) << 2);
    #pragma unroll
    for (int ti = 0; ti < 4; ++ti) {
        const int i = ti * 16 + i15;
        const float Ei = __expf(__shfl(acs, i, 64));
        float4 o;
        o.x = accY[ti][0] + Ei * accI[ti][0];
        o.y = accY[ti][1] + Ei * accI[ti][1];
        o.z = accY[ti][2] + Ei * accI[ti][2];
        o.w = accY[ti][3] + Ei * accI[ti][3];
        *(float4*)&Yg[((unsigned)(row0 + i) * NH + h) * 64 + pbase] = o;
    }
}

extern "C" void kernel_launch(void* const* d_in, const int* in_sizes, int n_in,
                              void* d_out, int out_size, void* d_ws, size_t ws_size,
                              hipStream_t stream) {
    const float* X = (const float*)d_in[0];
    const float* A = (const float*)d_in[1];
    const float* Bm = (const float*)d_in[2];
    const float* Cm = (const float*)d_in[3];
    float* Y = (float*)d_out;
    unsigned short* hws = (unsigned short*)d_ws;        // 16.8 MB
    unsigned short* Mws = hws + TILE_USHORTS;           // 16.8 MB
    float* dws = (float*)(Mws + TILE_USHORTS);          // 8 KB (chunk decays, exp form)

    ssd_f<<<NCH, 512, 0, stream>>>(X, A, Bm, Cm, hws, Mws, dws);
    ssd_scan<<<BSZ * NH * SCAN_G, 256, 0, stream>>>(hws, dws);
    ssd_y<<<NCH, 256, 0, stream>>>(X, A, Cm, Mws, hws, Y);
}